// Round 3
// baseline (2395.790 us; speedup 1.0000x reference)
//
#include <hip/hip_runtime.h>
#include <hip/hip_bf16.h>

#define TPB 256

// ---------------------------------------------------------------------------
// Generic fp32 tiled GEMM with optional bias: C(M,Nc) = A(M,K) @ W(K,Nc) + bias
// BM=BN=64, BK=16, 256 threads, 4x4 micro-tile per thread.
// ---------------------------------------------------------------------------
__global__ __launch_bounds__(TPB) void gemm_bias_k(
    const float* __restrict__ A, const float* __restrict__ W,
    const float* __restrict__ bias, float* __restrict__ C,
    int M, int K, int Nc)
{
  const int BM = 64, BN = 64, BK = 16;
  __shared__ float As[16][68];   // [k][row], padded to avoid bank conflicts
  __shared__ float Ws[16][68];   // [k][col]
  int tid = threadIdx.x;
  int row0 = blockIdx.y * BM;
  int col0 = blockIdx.x * BN;
  int ty = tid >> 4, tx = tid & 15;
  float acc[4][4] = {};
  for (int k0 = 0; k0 < K; k0 += BK) {
#pragma unroll
    for (int i = 0; i < 4; ++i) {       // A tile: 64 rows x 16 k
      int idx = tid + i * 256;
      int r  = idx >> 4;
      int kk = idx & 15;
      int gr = row0 + r, gk = k0 + kk;
      float v = 0.f;
      if (gr < M && gk < K) v = A[(size_t)gr * K + gk];
      As[kk][r] = v;
    }
#pragma unroll
    for (int i = 0; i < 4; ++i) {       // W tile: 16 k x 64 cols (coalesced)
      int idx = tid + i * 256;
      int c  = idx & 63;
      int kk = idx >> 6;
      int gc = col0 + c, gk = k0 + kk;
      float v = 0.f;
      if (gk < K && gc < Nc) v = W[(size_t)gk * Nc + gc];
      Ws[kk][c] = v;
    }
    __syncthreads();
#pragma unroll
    for (int kk = 0; kk < BK; ++kk) {
      float4 a4 = *(const float4*)&As[kk][ty * 4];
      float4 b4 = *(const float4*)&Ws[kk][tx * 4];
      float av[4] = {a4.x, a4.y, a4.z, a4.w};
      float bv[4] = {b4.x, b4.y, b4.z, b4.w};
#pragma unroll
      for (int i = 0; i < 4; ++i)
#pragma unroll
        for (int j = 0; j < 4; ++j)
          acc[i][j] = fmaf(av[i], bv[j], acc[i][j]);
    }
    __syncthreads();
  }
#pragma unroll
  for (int i = 0; i < 4; ++i) {
    int gr = row0 + ty * 4 + i;
    if (gr >= M) continue;
#pragma unroll
    for (int j = 0; j < 4; ++j) {
      int gc = col0 + tx * 4 + j;
      if (gc < Nc) {
        float v = acc[i][j];
        if (bias) v += bias[gc];
        C[(size_t)gr * Nc + gc] = v;
      }
    }
  }
}

// ---------------------------------------------------------------------------
// Attention: for each (h,b): scores = r@u^T (961x961), softmax rows, o=attn@v.
// ruv layout: [b][n][c], c = (t*12+h)*64+d, t=0:r 1:u 2:v.
// O layout: [hb][n*64+d], hb = h*8+b.
// Block: 256 thr, QB=8 queries, KT=32-key LDS tiles. fp32.
// ---------------------------------------------------------------------------
__global__ __launch_bounds__(TPB) void attn_k(
    const float* __restrict__ ruv, float* __restrict__ O)
{
  const int NS = 961, RS = 2304;
  const int QB = 8, KT = 32;
  __shared__ float tile[KT][68];    // u or v tile
  __shared__ float s_p[QB][962];    // logits -> probabilities
  int hb = blockIdx.y;
  int h = hb >> 3, b = hb & 7;
  int n0 = blockIdx.x * QB;
  int tid = threadIdx.x;
  int q  = tid >> 5;      // 0..7
  int ml = tid & 31;      // 0..31
  const float* base = ruv + (size_t)b * NS * RS;
  int roff = h * 64, uoff = 768 + h * 64, voff = 1536 + h * 64;

  // r row for this thread's query, in registers (shared by 32 lanes of same q)
  float4 r4[16];
  {
    int n = n0 + q;
    if (n < NS) {
      const float* rp = base + (size_t)n * RS + roff;
#pragma unroll
      for (int k = 0; k < 16; ++k) r4[k] = *(const float4*)(rp + k * 4);
    } else {
#pragma unroll
      for (int k = 0; k < 16; ++k) r4[k] = make_float4(0.f, 0.f, 0.f, 0.f);
    }
  }

  // ---- phase 1: logits ----
  for (int m0 = 0; m0 < NS; m0 += KT) {
    int mt = NS - m0; if (mt > KT) mt = KT;
#pragma unroll
    for (int i = 0; i < 8; ++i) {       // load u tile (coalesced)
      int idx = tid + i * 256;
      int mm = idx >> 6, d = idx & 63;
      float v = 0.f;
      if (mm < mt) v = base[(size_t)(m0 + mm) * RS + uoff + d];
      tile[mm][d] = v;
    }
    __syncthreads();
    if (ml < mt) {
      float s = 0.f;
#pragma unroll
      for (int k = 0; k < 16; ++k) {
        float4 u4 = *(const float4*)&tile[ml][k * 4];
        s += r4[k].x * u4.x + r4[k].y * u4.y + r4[k].z * u4.z + r4[k].w * u4.w;
      }
      s_p[q][m0 + ml] = s;
    }
    __syncthreads();
  }

  // ---- phase 2: softmax per q row (32 lanes per row, same wave) ----
  float lmax = -1e30f;
  for (int m = ml; m < NS; m += 32) lmax = fmaxf(lmax, s_p[q][m]);
#pragma unroll
  for (int off = 16; off >= 1; off >>= 1)
    lmax = fmaxf(lmax, __shfl_xor(lmax, off, 64));
  float lsum = 0.f;
  for (int m = ml; m < NS; m += 32) {
    float e = __expf(s_p[q][m] - lmax);
    s_p[q][m] = e;
    lsum += e;
  }
#pragma unroll
  for (int off = 16; off >= 1; off >>= 1) lsum += __shfl_xor(lsum, off, 64);
  float inv = 1.f / lsum;

  // ---- phase 3: o = P @ V. thread -> (q, dims 2*ml, 2*ml+1) ----
  int dl = ml;
  float2 accv = make_float2(0.f, 0.f);
  for (int m0 = 0; m0 < NS; m0 += KT) {
    int mt = NS - m0; if (mt > KT) mt = KT;
    __syncthreads();                    // tile reuse + s_p visibility
#pragma unroll
    for (int i = 0; i < 8; ++i) {       // load v tile (coalesced)
      int idx = tid + i * 256;
      int mm = idx >> 6, d = idx & 63;
      float v = 0.f;
      if (mm < mt) v = base[(size_t)(m0 + mm) * RS + voff + d];
      tile[mm][d] = v;
    }
    __syncthreads();
    for (int mi = 0; mi < mt; ++mi) {
      float p = s_p[q][m0 + mi];
      float2 v2 = *(const float2*)&tile[mi][dl * 2];
      accv.x += p * v2.x;
      accv.y += p * v2.y;
    }
  }
  int n = n0 + q;
  if (n < NS) {
    float2 o2 = make_float2(accv.x * inv, accv.y * inv);
    *(float2*)&O[(size_t)hb * 61504 + (size_t)n * 64 + dl * 2] = o2;
  }
}

// ---------------------------------------------------------------------------
// wfold[m] = Wp1[m,:] . Wp2   (378 MB read of Wp1, memory-bound)
// one wave per m, 4 m per block.
// ---------------------------------------------------------------------------
__global__ __launch_bounds__(TPB) void fold_wp_k(
    const float* __restrict__ Wp1, const float* __restrict__ Wp2,
    float* __restrict__ wfold)
{
  __shared__ float w2[1536];
  int tid = threadIdx.x;
  for (int i = tid; i < 1536; i += 256) w2[i] = Wp2[i];
  __syncthreads();
  int lane = tid & 63, wv = tid >> 6;
  int m = blockIdx.x * 4 + wv;
  if (m >= 61504) return;
  const float* row = Wp1 + (size_t)m * 1536;
  float s = 0.f;
#pragma unroll
  for (int k = 0; k < 6; ++k) {
    float4 a  = *(const float4*)(row + k * 256 + lane * 4);
    float4 w4 = *(const float4*)&w2[k * 256 + lane * 4];
    s += a.x * w4.x + a.y * w4.y + a.z * w4.z + a.w * w4.w;
  }
#pragma unroll
  for (int off = 32; off >= 1; off >>= 1) s += __shfl_xor(s, off, 64);
  if (lane == 0) wfold[m] = s;
}

// ---------------------------------------------------------------------------
// out[b*12+h] = O[hb,:] . wfold + bp1 . Wp2 + bp2
// ---------------------------------------------------------------------------
__global__ __launch_bounds__(TPB) void final_k(
    const float* __restrict__ O, const float* __restrict__ wfold,
    const float* __restrict__ bp1, const float* __restrict__ Wp2,
    const float* __restrict__ bp2, float* __restrict__ out)
{
  int hb = blockIdx.x;
  int h = hb >> 3, b = hb & 7;
  int tid = threadIdx.x;
  const float* orow = O + (size_t)hb * 61504;
  float s = 0.f;
  for (int i4 = tid; i4 < 15376; i4 += 256) {
    float4 a = *(const float4*)(orow + (size_t)i4 * 4);
    float4 w = *(const float4*)(wfold + (size_t)i4 * 4);
    s += a.x * w.x + a.y * w.y + a.z * w.z + a.w * w.w;
  }
  for (int p = tid; p < 1536; p += 256) s += bp1[p] * Wp2[p];
#pragma unroll
  for (int off = 32; off >= 1; off >>= 1) s += __shfl_xor(s, off, 64);
  __shared__ float red[4];
  if ((tid & 63) == 0) red[tid >> 6] = s;
  __syncthreads();
  if (tid == 0) out[b * 12 + h] = red[0] + red[1] + red[2] + red[3] + bp2[0];
}

// ---------------------------------------------------------------------------
extern "C" void kernel_launch(void* const* d_in, const int* in_sizes, int n_in,
                              void* d_out, int out_size, void* d_ws, size_t ws_size,
                              hipStream_t stream)
{
  const float* x    = (const float*)d_in[0];
  const float* W1   = (const float*)d_in[1];
  const float* b1   = (const float*)d_in[2];
  const float* W2   = (const float*)d_in[3];
  const float* b2   = (const float*)d_in[4];
  const float* W3   = (const float*)d_in[5];
  const float* b3   = (const float*)d_in[6];
  const float* W4   = (const float*)d_in[7];
  const float* b4   = (const float*)d_in[8];
  const float* Wruv = (const float*)d_in[9];
  const float* bruv = (const float*)d_in[10];
  const float* Wp1  = (const float*)d_in[11];
  const float* bp1  = (const float*)d_in[12];
  const float* Wp2  = (const float*)d_in[13];
  const float* bp2  = (const float*)d_in[14];
  float* out = (float*)d_out;

  float* ws = (float*)d_ws;
  size_t off = 0;
  auto alloc = [&](size_t n) { float* p = ws + off; off += n; return p; };
  float* ruvb  = alloc((size_t)7688 * 2304);   // 71 MB
  float* Ob    = alloc((size_t)96 * 61504);    // 23.6 MB
  float* Wa    = alloc(50 * 200);
  float* ba    = alloc(200);
  float* Wb    = alloc(50 * 200);
  float* bb    = alloc(200);
  float* Wc    = alloc(50 * 768);
  float* bc    = alloc(768);
  float* Wf    = alloc(50 * 2304);
  float* bfv   = alloc(2304);
  float* wfold = alloc(61504);
  if (off * sizeof(float) > ws_size) return;   // visible failure if ws too small

  dim3 tb(TPB);
  auto g2 = [](int M, int Nc) { return dim3((unsigned)((Nc + 63) / 64), (unsigned)((M + 63) / 64)); };

  // ---- fold the linear MLP + RUV projection into one 50x2304 affine map ----
  gemm_bias_k<<<g2(50, 200),  tb, 0, stream>>>(W1, W2, nullptr, Wa, 50, 200, 200);
  gemm_bias_k<<<g2(1,  200),  tb, 0, stream>>>(b1, W2, b2,      ba, 1,  200, 200);
  gemm_bias_k<<<g2(50, 200),  tb, 0, stream>>>(Wa, W3, nullptr, Wb, 50, 200, 200);
  gemm_bias_k<<<g2(1,  200),  tb, 0, stream>>>(ba, W3, b3,      bb, 1,  200, 200);
  gemm_bias_k<<<g2(50, 768),  tb, 0, stream>>>(Wb, W4, nullptr, Wc, 50, 200, 768);
  gemm_bias_k<<<g2(1,  768),  tb, 0, stream>>>(bb, W4, b4,      bc, 1,  200, 768);
  gemm_bias_k<<<g2(50, 2304), tb, 0, stream>>>(Wc, Wruv, nullptr, Wf, 50, 768, 2304);
  gemm_bias_k<<<g2(1,  2304), tb, 0, stream>>>(bc, Wruv, bruv,    bfv, 1, 768, 2304);

  // ---- ruv = x @ Wf + bf  (7688 x 50 -> 2304) ----
  gemm_bias_k<<<g2(7688, 2304), tb, 0, stream>>>(x, Wf, bfv, ruvb, 7688, 50, 2304);

  // ---- attention ----
  attn_k<<<dim3(121, 96), tb, 0, stream>>>(ruvb, Ob);

  // ---- fold Wp1 @ Wp2 (memory-bound, 378 MB) ----
  fold_wp_k<<<dim3(15376), tb, 0, stream>>>(Wp1, Wp2, wfold);

  // ---- final scalar per (h,b) ----
  final_k<<<dim3(96), tb, 0, stream>>>(Ob, wfold, bp1, Wp2, bp2, out);
}

// Round 6
// 636.349 us; speedup vs baseline: 3.7649x; 3.7649x over previous
//
#include <hip/hip_runtime.h>
#include <hip/hip_bf16.h>

#define TPB 256

typedef __attribute__((ext_vector_type(8))) short bf16x8;
typedef __attribute__((ext_vector_type(4))) float f32x4;

static __device__ __forceinline__ unsigned short f2bf(float f) {
  union { float f; unsigned int u; } x; x.f = f;
  unsigned int r = x.u + 0x7FFF + ((x.u >> 16) & 1);   // RNE
  return (unsigned short)(r >> 16);
}

#define MFMA16(a, b, c) __builtin_amdgcn_mfma_f32_16x16x32_bf16(a, b, c, 0, 0, 0)

// ---------------------------------------------------------------------------
// Generic fp32 tiled GEMM with optional bias: C(M,Nc) = A(M,K) @ W(K,Nc) + bias
// Used only for the tiny weight-folding chain.
// ---------------------------------------------------------------------------
__global__ __launch_bounds__(TPB) void gemm_bias_k(
    const float* __restrict__ A, const float* __restrict__ W,
    const float* __restrict__ bias, float* __restrict__ C,
    int M, int K, int Nc)
{
  const int BK = 16;
  __shared__ float As[16][68];
  __shared__ float Ws[16][68];
  int tid = threadIdx.x;
  int row0 = blockIdx.y * 64;
  int col0 = blockIdx.x * 64;
  int ty = tid >> 4, tx = tid & 15;
  float acc[4][4] = {};
  for (int k0 = 0; k0 < K; k0 += BK) {
#pragma unroll
    for (int i = 0; i < 4; ++i) {
      int idx = tid + i * 256;
      int r = idx >> 4, kk = idx & 15;
      int gr = row0 + r, gk = k0 + kk;
      float v = 0.f;
      if (gr < M && gk < K) v = A[(size_t)gr * K + gk];
      As[kk][r] = v;
    }
#pragma unroll
    for (int i = 0; i < 4; ++i) {
      int idx = tid + i * 256;
      int c = idx & 63, kk = idx >> 6;
      int gc = col0 + c, gk = k0 + kk;
      float v = 0.f;
      if (gk < K && gc < Nc) v = W[(size_t)gk * Nc + gc];
      Ws[kk][c] = v;
    }
    __syncthreads();
#pragma unroll
    for (int kk = 0; kk < BK; ++kk) {
      float4 a4 = *(const float4*)&As[kk][ty * 4];
      float4 b4 = *(const float4*)&Ws[kk][tx * 4];
      float av[4] = {a4.x, a4.y, a4.z, a4.w};
      float bv[4] = {b4.x, b4.y, b4.z, b4.w};
#pragma unroll
      for (int i = 0; i < 4; ++i)
#pragma unroll
        for (int j = 0; j < 4; ++j)
          acc[i][j] = fmaf(av[i], bv[j], acc[i][j]);
    }
    __syncthreads();
  }
#pragma unroll
  for (int i = 0; i < 4; ++i) {
    int gr = row0 + ty * 4 + i;
    if (gr >= M) continue;
#pragma unroll
    for (int j = 0; j < 4; ++j) {
      int gc = col0 + tx * 4 + j;
      if (gc < Nc) {
        float v = acc[i][j];
        if (bias) v += bias[gc];
        C[(size_t)gr * Nc + gc] = v;
      }
    }
  }
}

// ---------------------------------------------------------------------------
// ruv = x @ Wf + bfv, with bf16 outputs split into:
//   RU[gr][1536]   (r and u parts, row-major bf16)
//   Vt[hb][d][968] (v part, transposed per head; hb = h*8 + b to MATCH reader)
// M=7688, K=50, N=2304. Grid (36, 121).
// ---------------------------------------------------------------------------
__global__ __launch_bounds__(TPB) void gemm_ruv_k(
    const float* __restrict__ A, const float* __restrict__ W,
    const float* __restrict__ bias,
    unsigned short* __restrict__ RU, unsigned short* __restrict__ Vt)
{
  const int M = 7688, K = 50, Nc = 2304;
  __shared__ float As[16][68];
  __shared__ float Ws[16][68];
  int tid = threadIdx.x;
  int row0 = blockIdx.y * 64;
  int col0 = blockIdx.x * 64;
  int ty = tid >> 4, tx = tid & 15;
  float acc[4][4] = {};
  for (int k0 = 0; k0 < K; k0 += 16) {
#pragma unroll
    for (int i = 0; i < 4; ++i) {
      int idx = tid + i * 256;
      int r = idx >> 4, kk = idx & 15;
      int gr = row0 + r, gk = k0 + kk;
      float v = 0.f;
      if (gr < M && gk < K) v = A[(size_t)gr * K + gk];
      As[kk][r] = v;
    }
#pragma unroll
    for (int i = 0; i < 4; ++i) {
      int idx = tid + i * 256;
      int c = idx & 63, kk = idx >> 6;
      int gc = col0 + c, gk = k0 + kk;
      float v = 0.f;
      if (gk < K && gc < Nc) v = W[(size_t)gk * Nc + gc];
      Ws[kk][c] = v;
    }
    __syncthreads();
#pragma unroll
    for (int kk = 0; kk < 16; ++kk) {
      float4 a4 = *(const float4*)&As[kk][ty * 4];
      float4 b4 = *(const float4*)&Ws[kk][tx * 4];
      float av[4] = {a4.x, a4.y, a4.z, a4.w};
      float bv[4] = {b4.x, b4.y, b4.z, b4.w};
#pragma unroll
      for (int i = 0; i < 4; ++i)
#pragma unroll
        for (int j = 0; j < 4; ++j)
          acc[i][j] = fmaf(av[i], bv[j], acc[i][j]);
    }
    __syncthreads();
  }
  int c0 = col0 + tx * 4;
  if (col0 < 1536) {
    // r/u columns -> RU row-major bf16 (row stride 1536)
#pragma unroll
    for (int i = 0; i < 4; ++i) {
      int gr = row0 + ty * 4 + i;
      if (gr >= M) continue;
      ushort4 o;
      o.x = f2bf(acc[i][0] + bias[c0 + 0]);
      o.y = f2bf(acc[i][1] + bias[c0 + 1]);
      o.z = f2bf(acc[i][2] + bias[c0 + 2]);
      o.w = f2bf(acc[i][3] + bias[c0 + 3]);
      *(ushort4*)&RU[(size_t)gr * 1536 + c0] = o;
    }
  } else {
    // v columns -> Vt[h*8+b][d][968] transposed (scalar stores; boundary-safe)
#pragma unroll
    for (int j = 0; j < 4; ++j) {
      int c = c0 + j;
      int hd = c - 1536;
      int hh = hd >> 6, d = hd & 63;
#pragma unroll
      for (int i = 0; i < 4; ++i) {
        int gr = row0 + ty * 4 + i;
        if (gr >= M) continue;
        int b = gr / 961;
        int nl = gr - b * 961;
        Vt[((size_t)(hh * 8 + b) * 64 + d) * 968 + nl] = f2bf(acc[i][j] + bias[c]);
      }
    }
  }
}

// ---------------------------------------------------------------------------
// MFMA flash attention (no-max softmax: logits bounded << 87).
// Per block: 64 queries x one (h,b). 4 waves, each owns 16 q rows.
// K-tiles of 64 keys staged in LDS (XOR-swizzled); P staged per-wave in LDS.
// QK^T col-tile ct covers keys {c*4+ct} so exp() pairs pack into b32 writes.
// rowsum accumulates the bf16-ROUNDED P values so numerator (bf16 PV MFMA)
// and denominator match exactly to rounding order.
// ---------------------------------------------------------------------------
__global__ __launch_bounds__(TPB) void attn_mfma_k(
    const unsigned short* __restrict__ RU,   // [b*961][1536] bf16 bits
    const unsigned short* __restrict__ Vt,   // [hb][64][968] bf16 bits
    float* __restrict__ O)                   // [hb][961*64] fp32
{
  const int NS = 961, RS = 1536, VROW = 968;
  __shared__ unsigned short Kl[64 * 64];
  __shared__ unsigned short Vl[64 * 64];
  __shared__ unsigned short Pl[4][16 * 64];
  int hb = blockIdx.y;
  int h = hb >> 3, b = hb & 7;
  int n0 = blockIdx.x * 64;
  int tid = threadIdx.x;
  int w = tid >> 6, lane = tid & 63;
  int g = lane >> 4, c = lane & 15;
  const unsigned short* rubase = RU + (size_t)b * NS * RS;
  int roff = h * 64, uoff = 768 + h * 64;
  const unsigned short* vtbase = Vt + (size_t)hb * 64 * VROW;
  unsigned short* pw = &Pl[w][0];

  // Q fragments (A-operand): row = c, k = kk*32 + g*8 + i
  int qrow = n0 + w * 16 + c;
  if (qrow > 960) qrow = 960;
  bf16x8 qf0 = *(const bf16x8*)(rubase + (size_t)qrow * RS + roff + g * 8);
  bf16x8 qf1 = *(const bf16x8*)(rubase + (size_t)qrow * RS + roff + 32 + g * 8);

  f32x4 zero4 = {0.f, 0.f, 0.f, 0.f};
  f32x4 oacc[4] = {zero4, zero4, zero4, zero4};
  float rowsum[4] = {0.f, 0.f, 0.f, 0.f};

  for (int kt = 0; kt < 16; ++kt) {
    // ---- stage K(u) and V tiles ----
#pragma unroll
    for (int it = 0; it < 2; ++it) {
      int chunk = tid + it * 256;     // 512 chunks of 8 bf16
      int row = chunk >> 3, s = chunk & 7;
      int keyg = kt * 64 + row;
      int kcl = keyg > 960 ? 960 : keyg;
      ushort4 ka = *(const ushort4*)(rubase + (size_t)kcl * RS + uoff + s * 8);
      ushort4 kb = *(const ushort4*)(rubase + (size_t)kcl * RS + uoff + s * 8 + 4);
      int kel = row * 64 + 8 * (s ^ (row & 7));
      *(ushort4*)&Kl[kel] = ka;
      *(ushort4*)&Kl[kel + 4] = kb;

      int d = row;
      int koff = kt * 64 + s * 8;
      ushort4 va = *(const ushort4*)(vtbase + (size_t)d * VROW + koff);
      ushort4 vb = *(const ushort4*)(vtbase + (size_t)d * VROW + koff + 4);
      unsigned short vv[8] = {va.x, va.y, va.z, va.w, vb.x, vb.y, vb.z, vb.w};
#pragma unroll
      for (int e = 0; e < 8; ++e)
        if (koff + e > 960) vv[e] = 0;
      int vel = d * 64 + 8 * (s ^ (d & 7));
#pragma unroll
      for (int e = 0; e < 8; ++e) Vl[vel + e] = vv[e];
    }
    __syncthreads();

    // ---- QK^T: S[q][key], col-tile ct -> keys {c*4+ct} ----
    f32x4 sa[4] = {zero4, zero4, zero4, zero4};
#pragma unroll
    for (int ct = 0; ct < 4; ++ct) {
      int key = c * 4 + ct;
      const bf16x8* kf0 = (const bf16x8*)&Kl[key * 64 + ((g * 8) ^ ((key & 7) * 8))];
      const bf16x8* kf1 = (const bf16x8*)&Kl[key * 64 + ((32 + g * 8) ^ ((key & 7) * 8))];
      sa[ct] = MFMA16(qf0, *kf0, sa[ct]);
      sa[ct] = MFMA16(qf1, *kf1, sa[ct]);
    }

    // ---- exp (no max), mask, pack P (bf16), rowsum from ROUNDED values ----
#pragma unroll
    for (int r = 0; r < 4; ++r) {
      unsigned short pb[4];
#pragma unroll
      for (int ct = 0; ct < 4; ++ct) {
        int keyg = kt * 64 + c * 4 + ct;
        unsigned short p16 = 0;
        if (keyg <= 960) p16 = f2bf(__expf(sa[ct][r]));
        pb[ct] = p16;
        union { unsigned int u; float f; } bu;
        bu.u = (unsigned int)p16 << 16;
        rowsum[r] += bu.f;
      }
      int q = g * 4 + r;
      unsigned int p01 = (unsigned int)pb[0] | ((unsigned int)pb[1] << 16);
      unsigned int p23 = (unsigned int)pb[2] | ((unsigned int)pb[3] << 16);
      int e0 = (c * 4) ^ ((q & 7) * 8);
      *(unsigned int*)&pw[q * 64 + e0] = p01;
      *(unsigned int*)&pw[q * 64 + e0 + 2] = p23;
    }
    __syncthreads();   // P visible; K reads complete

    // ---- PV: O[q][d] += P @ V ----
#pragma unroll
    for (int kk = 0; kk < 2; ++kk) {
      bf16x8 pa = *(const bf16x8*)&pw[c * 64 + ((kk * 32 + g * 8) ^ ((c & 7) * 8))];
#pragma unroll
      for (int dt = 0; dt < 4; ++dt) {
        int d = dt * 16 + c;
        const bf16x8* vf = (const bf16x8*)&Vl[d * 64 + ((kk * 32 + g * 8) ^ ((d & 7) * 8))];
        oacc[dt] = MFMA16(pa, *vf, oacc[dt]);
      }
    }
    __syncthreads();   // tiles may be restaged
  }

  // ---- finalize: rowsum reduce over the 16-lane col groups, scale, store ----
#pragma unroll
  for (int r = 0; r < 4; ++r) {
    float s = rowsum[r];
    s += __shfl_xor(s, 1, 64);
    s += __shfl_xor(s, 2, 64);
    s += __shfl_xor(s, 4, 64);
    s += __shfl_xor(s, 8, 64);
    rowsum[r] = 1.f / s;
  }
  int nbase = n0 + w * 16 + g * 4;
  float* ob = O + (size_t)hb * 61504;
#pragma unroll
  for (int r = 0; r < 4; ++r) {
    int n = nbase + r;
    if (n > 960) continue;
#pragma unroll
    for (int dt = 0; dt < 4; ++dt)
      ob[(size_t)n * 64 + dt * 16 + c] = oacc[dt][r] * rowsum[r];
  }
}

// ---------------------------------------------------------------------------
// wfold[m] = Wp1[m,:] . Wp2   (378 MB read, HBM-bound)
// ---------------------------------------------------------------------------
__global__ __launch_bounds__(TPB) void fold_wp_k(
    const float* __restrict__ Wp1, const float* __restrict__ Wp2,
    float* __restrict__ wfold)
{
  __shared__ float w2[1536];
  int tid = threadIdx.x;
  for (int i = tid; i < 1536; i += 256) w2[i] = Wp2[i];
  __syncthreads();
  int lane = tid & 63, wv = tid >> 6;
  int m = blockIdx.x * 4 + wv;
  if (m >= 61504) return;
  const float* row = Wp1 + (size_t)m * 1536;
  float s = 0.f;
#pragma unroll
  for (int k = 0; k < 6; ++k) {
    float4 a  = *(const float4*)(row + k * 256 + lane * 4);
    float4 w4 = *(const float4*)&w2[k * 256 + lane * 4];
    s += a.x * w4.x + a.y * w4.y + a.z * w4.z + a.w * w4.w;
  }
#pragma unroll
  for (int off = 32; off >= 1; off >>= 1) s += __shfl_xor(s, off, 64);
  if (lane == 0) wfold[m] = s;
}

// ---------------------------------------------------------------------------
// out[b*12+h] = O[hb,:] . wfold + bp1 . Wp2 + bp2
// ---------------------------------------------------------------------------
__global__ __launch_bounds__(TPB) void final_k(
    const float* __restrict__ O, const float* __restrict__ wfold,
    const float* __restrict__ bp1, const float* __restrict__ Wp2,
    const float* __restrict__ bp2, float* __restrict__ out)
{
  int hb = blockIdx.x;
  int h = hb >> 3, b = hb & 7;
  int tid = threadIdx.x;
  const float* orow = O + (size_t)hb * 61504;
  float s = 0.f;
  for (int i4 = tid; i4 < 15376; i4 += 256) {
    float4 a = *(const float4*)(orow + (size_t)i4 * 4);
    float4 w = *(const float4*)(wfold + (size_t)i4 * 4);
    s += a.x * w.x + a.y * w.y + a.z * w.z + a.w * w.w;
  }
  for (int p = tid; p < 1536; p += 256) s += bp1[p] * Wp2[p];
#pragma unroll
  for (int off = 32; off >= 1; off >>= 1) s += __shfl_xor(s, off, 64);
  __shared__ float red[4];
  if ((tid & 63) == 0) red[tid >> 6] = s;
  __syncthreads();
  if (tid == 0) out[b * 12 + h] = red[0] + red[1] + red[2] + red[3] + bp2[0];
}

// ---------------------------------------------------------------------------
extern "C" void kernel_launch(void* const* d_in, const int* in_sizes, int n_in,
                              void* d_out, int out_size, void* d_ws, size_t ws_size,
                              hipStream_t stream)
{
  const float* x    = (const float*)d_in[0];
  const float* W1   = (const float*)d_in[1];
  const float* b1   = (const float*)d_in[2];
  const float* W2   = (const float*)d_in[3];
  const float* b2   = (const float*)d_in[4];
  const float* W3   = (const float*)d_in[5];
  const float* b3   = (const float*)d_in[6];
  const float* W4   = (const float*)d_in[7];
  const float* b4   = (const float*)d_in[8];
  const float* Wruv = (const float*)d_in[9];
  const float* bruv = (const float*)d_in[10];
  const float* Wp1  = (const float*)d_in[11];
  const float* bp1  = (const float*)d_in[12];
  const float* Wp2  = (const float*)d_in[13];
  const float* bp2  = (const float*)d_in[14];
  float* out = (float*)d_out;

  char* base = (char*)d_ws;
  size_t off = 0;
  auto alloc = [&](size_t bytes) -> void* {
    void* p = base + off;
    off = (off + bytes + 255) & ~(size_t)255;
    return p;
  };
  unsigned short* RU  = (unsigned short*)alloc((size_t)7688 * 1536 * 2);     // 23.6 MB
  unsigned short* Vt  = (unsigned short*)alloc((size_t)96 * 64 * 968 * 2 + 1024); // 11.9 MB + pad
  float* Ob    = (float*)alloc((size_t)96 * 61504 * 4);                      // 23.6 MB
  float* Wa    = (float*)alloc(50 * 200 * 4);
  float* ba    = (float*)alloc(200 * 4);
  float* Wb    = (float*)alloc(50 * 200 * 4);
  float* bb    = (float*)alloc(200 * 4);
  float* Wc    = (float*)alloc(50 * 768 * 4);
  float* bc    = (float*)alloc(768 * 4);
  float* Wf    = (float*)alloc(50 * 2304 * 4);
  float* bfv   = (float*)alloc(2304 * 4);
  float* wfold = (float*)alloc(61504 * 4);
  if (off > ws_size) return;

  dim3 tb(TPB);
  auto g2 = [](int M, int Nc) { return dim3((unsigned)((Nc + 63) / 64), (unsigned)((M + 63) / 64)); };

  // ---- fold the linear MLP + RUV projection into one 50x2304 affine map ----
  gemm_bias_k<<<g2(50, 200),  tb, 0, stream>>>(W1, W2, nullptr, Wa, 50, 200, 200);
  gemm_bias_k<<<g2(1,  200),  tb, 0, stream>>>(b1, W2, b2,      ba, 1,  200, 200);
  gemm_bias_k<<<g2(50, 200),  tb, 0, stream>>>(Wa, W3, nullptr, Wb, 50, 200, 200);
  gemm_bias_k<<<g2(1,  200),  tb, 0, stream>>>(ba, W3, b3,      bb, 1,  200, 200);
  gemm_bias_k<<<g2(50, 768),  tb, 0, stream>>>(Wb, W4, nullptr, Wc, 50, 200, 768);
  gemm_bias_k<<<g2(1,  768),  tb, 0, stream>>>(bb, W4, b4,      bc, 1,  200, 768);
  gemm_bias_k<<<g2(50, 2304), tb, 0, stream>>>(Wc, Wruv, nullptr, Wf, 50, 768, 2304);
  gemm_bias_k<<<g2(1,  2304), tb, 0, stream>>>(bc, Wruv, bruv,    bfv, 1, 768, 2304);

  // ---- ruv = x @ Wf + bfv -> bf16 RU (r,u) + transposed Vt (v) ----
  gemm_ruv_k<<<dim3(36, 121), tb, 0, stream>>>(x, Wf, bfv, RU, Vt);

  // ---- MFMA flash attention ----
  attn_mfma_k<<<dim3(16, 96), tb, 0, stream>>>(RU, Vt, Ob);

  // ---- fold Wp1 @ Wp2 ----
  fold_wp_k<<<dim3(15376), tb, 0, stream>>>(Wp1, Wp2, wfold);

  // ---- final scalar per (h,b) ----
  final_k<<<dim3(96), tb, 0, stream>>>(Ob, wfold, bp1, Wp2, bp2, out);
}

// Round 7
// 497.070 us; speedup vs baseline: 4.8198x; 1.2802x over previous
//
#include <hip/hip_runtime.h>
#include <hip/hip_bf16.h>

#define TPB 256

typedef __attribute__((ext_vector_type(8))) short bf16x8;
typedef __attribute__((ext_vector_type(4))) float f32x4;

static __device__ __forceinline__ unsigned short f2bf(float f) {
  union { float f; unsigned int u; } x; x.f = f;
  unsigned int r = x.u + 0x7FFF + ((x.u >> 16) & 1);   // RNE
  return (unsigned short)(r >> 16);
}

#define MFMA16(a, b, c) __builtin_amdgcn_mfma_f32_16x16x32_bf16(a, b, c, 0, 0, 0)

// ---------------------------------------------------------------------------
// Augmented fold GEMM: C(51,Nc) = [A(50,K); lastrow(K)] @ W(K,Nc), bias added
// to row 50 only. mode 0: fp32 C row-major. mode 1: rows 0..49 (+51..63 zeros)
// -> WfT[col][64] bf16 with k pre-XOR-swizzled; row 50 -> bfv fp32.
// Grid: (ceil(Nc/64), 1), 256 threads.
// ---------------------------------------------------------------------------
__global__ __launch_bounds__(TPB) void gemm_fold_k(
    const float* __restrict__ A, const float* __restrict__ lastrow,
    const float* __restrict__ W, const float* __restrict__ bias,
    float* __restrict__ C, unsigned short* __restrict__ WfT,
    float* __restrict__ bfv, int K, int Nc, int mode)
{
  __shared__ float As[16][68];
  __shared__ float Ws[16][68];
  int tid = threadIdx.x;
  int col0 = blockIdx.x * 64;
  int ty = tid >> 4, tx = tid & 15;
  float acc[4][4] = {};
  for (int k0 = 0; k0 < K; k0 += 16) {
#pragma unroll
    for (int i = 0; i < 4; ++i) {
      int idx = tid + i * 256;
      int r = idx >> 4, kk = idx & 15;
      int gk = k0 + kk;
      float v = 0.f;
      if (gk < K) {
        if (r < 50) v = A[(size_t)r * K + gk];
        else if (r == 50) v = lastrow[gk];
      }
      As[kk][r] = v;
    }
#pragma unroll
    for (int i = 0; i < 4; ++i) {
      int idx = tid + i * 256;
      int c = idx & 63, kk = idx >> 6;
      int gc = col0 + c, gk = k0 + kk;
      float v = 0.f;
      if (gk < K && gc < Nc) v = W[(size_t)gk * Nc + gc];
      Ws[kk][c] = v;
    }
    __syncthreads();
#pragma unroll
    for (int kk = 0; kk < 16; ++kk) {
      float4 a4 = *(const float4*)&As[kk][ty * 4];
      float4 b4 = *(const float4*)&Ws[kk][tx * 4];
      float av[4] = {a4.x, a4.y, a4.z, a4.w};
      float bv[4] = {b4.x, b4.y, b4.z, b4.w};
#pragma unroll
      for (int i = 0; i < 4; ++i)
#pragma unroll
        for (int j = 0; j < 4; ++j)
          acc[i][j] = fmaf(av[i], bv[j], acc[i][j]);
    }
    __syncthreads();
  }
#pragma unroll
  for (int i = 0; i < 4; ++i) {
    int gr = ty * 4 + i;
#pragma unroll
    for (int j = 0; j < 4; ++j) {
      int gc = col0 + tx * 4 + j;
      if (gc >= Nc) continue;
      float v = acc[i][j];
      if (gr == 50) v += bias[gc];
      if (mode == 0) {
        if (gr < 51) C[(size_t)gr * Nc + gc] = v;
      } else {
        if (gr == 50) bfv[gc] = v;
        else WfT[(size_t)gc * 64 + (gr ^ ((gc & 7) * 8))] = f2bf(v);
      }
    }
  }
}

// ---------------------------------------------------------------------------
// MFMA ruv GEMM: [7688 x 50(->64)] bf16 @ WfT -> RU bf16 + Vt bf16 transposed.
// Block: 64 rows x 256 cols, 4 waves (wave w -> cols w*64..+63). Grid (9,121).
// A-fragments straight from global x (fp32->bf16 in reg); B staged LDS from
// pre-swizzled WfT (verbatim copy). Bias added in epilogue.
// Col blocks 0..5 are RU (cols<1536), 6..8 are Vt.
// ---------------------------------------------------------------------------
__global__ __launch_bounds__(TPB) void gemm_ruv_mfma_k(
    const float* __restrict__ x,             // [7688][50]
    const unsigned short* __restrict__ WfT,  // [2304][64] bf16, k swizzled
    const float* __restrict__ bias,          // [2304] fp32
    unsigned short* __restrict__ RU,         // [7688][1536]
    unsigned short* __restrict__ Vt)         // [hb][64][968], hb=h*8+b
{
  __shared__ unsigned short Bl[256 * 64];    // 32 KB
  int tid = threadIdx.x, w = tid >> 6, lane = tid & 63;
  int g = lane >> 4, c = lane & 15;
  int m0 = blockIdx.y * 64;
  int col0 = blockIdx.x * 256;

  // ---- stage B tile (verbatim, already swizzled) ----
#pragma unroll
  for (int it = 0; it < 8; ++it) {
    int chunk = tid + it * 256;
    int colr = chunk >> 3, s = chunk & 7;
    *(int4*)&Bl[colr * 64 + s * 8] =
        *(const int4*)&WfT[(size_t)(col0 + colr) * 64 + s * 8];
  }

  // ---- A fragments from global (rows m0+rt*16+c, k = kk*32+g*8+i) ----
  bf16x8 af[4][2];
#pragma unroll
  for (int rt = 0; rt < 4; ++rt) {
    int row = m0 + rt * 16 + c;
    if (row > 7687) row = 7687;
    const float* xr = x + (size_t)row * 50;
#pragma unroll
    for (int kk = 0; kk < 2; ++kk) {
      bf16x8 a;
#pragma unroll
      for (int i = 0; i < 8; ++i) {
        int k = kk * 32 + g * 8 + i;
        float v = (k < 50) ? xr[k] : 0.f;
        a[i] = (short)f2bf(v);
      }
      af[rt][kk] = a;
    }
  }
  __syncthreads();

  // ---- compute ----
  f32x4 zero4 = {0.f, 0.f, 0.f, 0.f};
  f32x4 acc[4][4] = {{zero4, zero4, zero4, zero4}, {zero4, zero4, zero4, zero4},
                     {zero4, zero4, zero4, zero4}, {zero4, zero4, zero4, zero4}};
  int wc0 = w * 64;
#pragma unroll
  for (int ct = 0; ct < 4; ++ct) {
    int bcol = wc0 + ct * 16 + c;
    int sw = (bcol & 7) * 8;
    bf16x8 b0 = *(const bf16x8*)&Bl[bcol * 64 + ((g * 8) ^ sw)];
    bf16x8 b1 = *(const bf16x8*)&Bl[bcol * 64 + ((32 + g * 8) ^ sw)];
#pragma unroll
    for (int rt = 0; rt < 4; ++rt) {
      acc[rt][ct] = MFMA16(af[rt][0], b0, acc[rt][ct]);
      acc[rt][ct] = MFMA16(af[rt][1], b1, acc[rt][ct]);
    }
  }

  // ---- epilogue: C row = m0+rt*16+g*4+r, col = col0+w*64+ct*16+c ----
  bool isRU = (col0 < 1536);
#pragma unroll
  for (int ct = 0; ct < 4; ++ct) {
    int col = col0 + wc0 + ct * 16 + c;
    float bs = bias[col];
    if (isRU) {
#pragma unroll
      for (int rt = 0; rt < 4; ++rt) {
        int row0 = m0 + rt * 16 + g * 4;
#pragma unroll
        for (int r = 0; r < 4; ++r) {
          int row = row0 + r;
          if (row < 7688)
            RU[(size_t)row * 1536 + col] = f2bf(acc[rt][ct][r] + bs);
        }
      }
    } else {
      int hd = col - 1536;
      int hh = hd >> 6, d = hd & 63;
#pragma unroll
      for (int rt = 0; rt < 4; ++rt) {
        int row0 = m0 + rt * 16 + g * 4;
        int b0 = row0 / 961;
        int n0 = row0 - b0 * 961;
        if (row0 + 3 < 7688 && n0 <= 957 && (n0 & 3) == 0) {
          ushort4 o;
          o.x = f2bf(acc[rt][ct][0] + bs);
          o.y = f2bf(acc[rt][ct][1] + bs);
          o.z = f2bf(acc[rt][ct][2] + bs);
          o.w = f2bf(acc[rt][ct][3] + bs);
          *(ushort4*)&Vt[((size_t)(hh * 8 + b0) * 64 + d) * 968 + n0] = o;
        } else {
#pragma unroll
          for (int r = 0; r < 4; ++r) {
            int row = row0 + r;
            if (row >= 7688) continue;
            int bb = row / 961;
            int nn = row - bb * 961;
            Vt[((size_t)(hh * 8 + bb) * 64 + d) * 968 + nn] =
                f2bf(acc[rt][ct][r] + bs);
          }
        }
      }
    }
  }
}

// ---------------------------------------------------------------------------
// MFMA flash attention (no-max softmax: logits bounded << 87). Unchanged.
// ---------------------------------------------------------------------------
__global__ __launch_bounds__(TPB) void attn_mfma_k(
    const unsigned short* __restrict__ RU,   // [b*961][1536] bf16 bits
    const unsigned short* __restrict__ Vt,   // [hb][64][968] bf16 bits
    float* __restrict__ O)                   // [hb][961*64] fp32
{
  const int NS = 961, RS = 1536, VROW = 968;
  __shared__ unsigned short Kl[64 * 64];
  __shared__ unsigned short Vl[64 * 64];
  __shared__ unsigned short Pl[4][16 * 64];
  int hb = blockIdx.y;
  int h = hb >> 3, b = hb & 7;
  int n0 = blockIdx.x * 64;
  int tid = threadIdx.x;
  int w = tid >> 6, lane = tid & 63;
  int g = lane >> 4, c = lane & 15;
  const unsigned short* rubase = RU + (size_t)b * NS * RS;
  int roff = h * 64, uoff = 768 + h * 64;
  const unsigned short* vtbase = Vt + (size_t)hb * 64 * VROW;
  unsigned short* pw = &Pl[w][0];

  int qrow = n0 + w * 16 + c;
  if (qrow > 960) qrow = 960;
  bf16x8 qf0 = *(const bf16x8*)(rubase + (size_t)qrow * RS + roff + g * 8);
  bf16x8 qf1 = *(const bf16x8*)(rubase + (size_t)qrow * RS + roff + 32 + g * 8);

  f32x4 zero4 = {0.f, 0.f, 0.f, 0.f};
  f32x4 oacc[4] = {zero4, zero4, zero4, zero4};
  float rowsum[4] = {0.f, 0.f, 0.f, 0.f};

  for (int kt = 0; kt < 16; ++kt) {
#pragma unroll
    for (int it = 0; it < 2; ++it) {
      int chunk = tid + it * 256;
      int row = chunk >> 3, s = chunk & 7;
      int keyg = kt * 64 + row;
      int kcl = keyg > 960 ? 960 : keyg;
      ushort4 ka = *(const ushort4*)(rubase + (size_t)kcl * RS + uoff + s * 8);
      ushort4 kb = *(const ushort4*)(rubase + (size_t)kcl * RS + uoff + s * 8 + 4);
      int kel = row * 64 + 8 * (s ^ (row & 7));
      *(ushort4*)&Kl[kel] = ka;
      *(ushort4*)&Kl[kel + 4] = kb;

      int d = row;
      int koff = kt * 64 + s * 8;
      ushort4 va = *(const ushort4*)(vtbase + (size_t)d * VROW + koff);
      ushort4 vb = *(const ushort4*)(vtbase + (size_t)d * VROW + koff + 4);
      unsigned short vv[8] = {va.x, va.y, va.z, va.w, vb.x, vb.y, vb.z, vb.w};
#pragma unroll
      for (int e = 0; e < 8; ++e)
        if (koff + e > 960) vv[e] = 0;
      int vel = d * 64 + 8 * (s ^ (d & 7));
#pragma unroll
      for (int e = 0; e < 8; ++e) Vl[vel + e] = vv[e];
    }
    __syncthreads();

    f32x4 sa[4] = {zero4, zero4, zero4, zero4};
#pragma unroll
    for (int ct = 0; ct < 4; ++ct) {
      int key = c * 4 + ct;
      const bf16x8* kf0 = (const bf16x8*)&Kl[key * 64 + ((g * 8) ^ ((key & 7) * 8))];
      const bf16x8* kf1 = (const bf16x8*)&Kl[key * 64 + ((32 + g * 8) ^ ((key & 7) * 8))];
      sa[ct] = MFMA16(qf0, *kf0, sa[ct]);
      sa[ct] = MFMA16(qf1, *kf1, sa[ct]);
    }

#pragma unroll
    for (int r = 0; r < 4; ++r) {
      unsigned short pb[4];
#pragma unroll
      for (int ct = 0; ct < 4; ++ct) {
        int keyg = kt * 64 + c * 4 + ct;
        unsigned short p16 = 0;
        if (keyg <= 960) p16 = f2bf(__expf(sa[ct][r]));
        pb[ct] = p16;
        union { unsigned int u; float f; } bu;
        bu.u = (unsigned int)p16 << 16;
        rowsum[r] += bu.f;
      }
      int q = g * 4 + r;
      unsigned int p01 = (unsigned int)pb[0] | ((unsigned int)pb[1] << 16);
      unsigned int p23 = (unsigned int)pb[2] | ((unsigned int)pb[3] << 16);
      int e0 = (c * 4) ^ ((q & 7) * 8);
      *(unsigned int*)&pw[q * 64 + e0] = p01;
      *(unsigned int*)&pw[q * 64 + e0 + 2] = p23;
    }
    __syncthreads();

#pragma unroll
    for (int kk = 0; kk < 2; ++kk) {
      bf16x8 pa = *(const bf16x8*)&pw[c * 64 + ((kk * 32 + g * 8) ^ ((c & 7) * 8))];
#pragma unroll
      for (int dt = 0; dt < 4; ++dt) {
        int d = dt * 16 + c;
        const bf16x8* vf = (const bf16x8*)&Vl[d * 64 + ((kk * 32 + g * 8) ^ ((d & 7) * 8))];
        oacc[dt] = MFMA16(pa, *vf, oacc[dt]);
      }
    }
    __syncthreads();
  }

#pragma unroll
  for (int r = 0; r < 4; ++r) {
    float s = rowsum[r];
    s += __shfl_xor(s, 1, 64);
    s += __shfl_xor(s, 2, 64);
    s += __shfl_xor(s, 4, 64);
    s += __shfl_xor(s, 8, 64);
    rowsum[r] = 1.f / s;
  }
  int nbase = n0 + w * 16 + g * 4;
  float* ob = O + (size_t)hb * 61504;
#pragma unroll
  for (int r = 0; r < 4; ++r) {
    int n = nbase + r;
    if (n > 960) continue;
#pragma unroll
    for (int dt = 0; dt < 4; ++dt)
      ob[(size_t)n * 64 + dt * 16 + c] = oacc[dt][r] * rowsum[r];
  }
}

// ---------------------------------------------------------------------------
// wfold[m] = Wp1[m,:] . Wp2   (378 MB read, HBM-bound)
// ---------------------------------------------------------------------------
__global__ __launch_bounds__(TPB) void fold_wp_k(
    const float* __restrict__ Wp1, const float* __restrict__ Wp2,
    float* __restrict__ wfold)
{
  __shared__ float w2[1536];
  int tid = threadIdx.x;
  for (int i = tid; i < 1536; i += 256) w2[i] = Wp2[i];
  __syncthreads();
  int lane = tid & 63, wv = tid >> 6;
  int m = blockIdx.x * 4 + wv;
  if (m >= 61504) return;
  const float* row = Wp1 + (size_t)m * 1536;
  float s = 0.f;
#pragma unroll
  for (int k = 0; k < 6; ++k) {
    float4 a  = *(const float4*)(row + k * 256 + lane * 4);
    float4 w4 = *(const float4*)&w2[k * 256 + lane * 4];
    s += a.x * w4.x + a.y * w4.y + a.z * w4.z + a.w * w4.w;
  }
#pragma unroll
  for (int off = 32; off >= 1; off >>= 1) s += __shfl_xor(s, off, 64);
  if (lane == 0) wfold[m] = s;
}

// ---------------------------------------------------------------------------
// out[b*12+h] = O[hb,:] . wfold + bp1 . Wp2 + bp2
// ---------------------------------------------------------------------------
__global__ __launch_bounds__(TPB) void final_k(
    const float* __restrict__ O, const float* __restrict__ wfold,
    const float* __restrict__ bp1, const float* __restrict__ Wp2,
    const float* __restrict__ bp2, float* __restrict__ out)
{
  int hb = blockIdx.x;
  int h = hb >> 3, b = hb & 7;
  int tid = threadIdx.x;
  const float* orow = O + (size_t)hb * 61504;
  float s = 0.f;
  for (int i4 = tid; i4 < 15376; i4 += 256) {
    float4 a = *(const float4*)(orow + (size_t)i4 * 4);
    float4 w = *(const float4*)(wfold + (size_t)i4 * 4);
    s += a.x * w.x + a.y * w.y + a.z * w.z + a.w * w.w;
  }
  for (int p = tid; p < 1536; p += 256) s += bp1[p] * Wp2[p];
#pragma unroll
  for (int off = 32; off >= 1; off >>= 1) s += __shfl_xor(s, off, 64);
  __shared__ float red[4];
  if ((tid & 63) == 0) red[tid >> 6] = s;
  __syncthreads();
  if (tid == 0) out[b * 12 + h] = red[0] + red[1] + red[2] + red[3] + bp2[0];
}

// ---------------------------------------------------------------------------
extern "C" void kernel_launch(void* const* d_in, const int* in_sizes, int n_in,
                              void* d_out, int out_size, void* d_ws, size_t ws_size,
                              hipStream_t stream)
{
  const float* x    = (const float*)d_in[0];
  const float* W1   = (const float*)d_in[1];
  const float* b1   = (const float*)d_in[2];
  const float* W2   = (const float*)d_in[3];
  const float* b2   = (const float*)d_in[4];
  const float* W3   = (const float*)d_in[5];
  const float* b3   = (const float*)d_in[6];
  const float* W4   = (const float*)d_in[7];
  const float* b4   = (const float*)d_in[8];
  const float* Wruv = (const float*)d_in[9];
  const float* bruv = (const float*)d_in[10];
  const float* Wp1  = (const float*)d_in[11];
  const float* bp1  = (const float*)d_in[12];
  const float* Wp2  = (const float*)d_in[13];
  const float* bp2  = (const float*)d_in[14];
  float* out = (float*)d_out;

  char* base = (char*)d_ws;
  size_t off = 0;
  auto alloc = [&](size_t bytes) -> void* {
    void* p = base + off;
    off = (off + bytes + 255) & ~(size_t)255;
    return p;
  };
  unsigned short* RU  = (unsigned short*)alloc((size_t)7688 * 1536 * 2);          // 23.6 MB
  unsigned short* Vt  = (unsigned short*)alloc((size_t)96 * 64 * 968 * 2 + 1024); // 11.9 MB
  float* Ob    = (float*)alloc((size_t)96 * 61504 * 4);                           // 23.6 MB
  float* aug1  = (float*)alloc(51 * 200 * 4);
  float* aug2  = (float*)alloc(51 * 200 * 4);
  float* aug3  = (float*)alloc(51 * 768 * 4);
  unsigned short* WfT = (unsigned short*)alloc((size_t)2304 * 64 * 2);
  float* bfv   = (float*)alloc(2304 * 4);
  float* wfold = (float*)alloc(61504 * 4);
  if (off > ws_size) return;

  dim3 tb(TPB);

  // ---- fold MLP+RUV into augmented [Wf; bf] via 4 GEMMs ----
  gemm_fold_k<<<dim3(4),  tb, 0, stream>>>(W1,   b1,            W2,   b2,   aug1, nullptr, nullptr, 200, 200, 0);
  gemm_fold_k<<<dim3(4),  tb, 0, stream>>>(aug1, aug1 + 50*200, W3,   b3,   aug2, nullptr, nullptr, 200, 200, 0);
  gemm_fold_k<<<dim3(12), tb, 0, stream>>>(aug2, aug2 + 50*200, W4,   b4,   aug3, nullptr, nullptr, 200, 768, 0);
  gemm_fold_k<<<dim3(36), tb, 0, stream>>>(aug3, aug3 + 50*768, Wruv, bruv, nullptr, WfT,  bfv,     768, 2304, 1);

  // ---- ruv = x @ Wf + bf (MFMA bf16) -> RU + transposed Vt ----
  gemm_ruv_mfma_k<<<dim3(9, 121), tb, 0, stream>>>(x, WfT, bfv, RU, Vt);

  // ---- MFMA flash attention ----
  attn_mfma_k<<<dim3(16, 96), tb, 0, stream>>>(RU, Vt, Ob);

  // ---- fold Wp1 @ Wp2 ----
  fold_wp_k<<<dim3(15376), tb, 0, stream>>>(Wp1, Wp2, wfold);

  // ---- final scalar per (h,b) ----
  final_k<<<dim3(96), tb, 0, stream>>>(Ob, wfold, bp1, Wp2, bp2, out);
}